// Round 10
// baseline (4063.466 us; speedup 1.0000x reference)
//
#include <hip/hip_runtime.h>
#include <hip/hip_bf16.h>
#include <math.h>

#define TT 1024
#define BB 256
#define LOG2PI 1.8378770664093453f

typedef short short8 __attribute__((ext_vector_type(8)));
typedef float f32x4  __attribute__((ext_vector_type(4)));

__device__ __forceinline__ float sigmoid_f(float x) {
    return 1.f / (1.f + __expf(-x));
}
__device__ __forceinline__ float tanh_f(float x) {
    return 1.f - 2.f / (__expf(2.f*x) + 1.f);
}
__device__ __forceinline__ unsigned short f2bf(float x) {   // RNE fp32->bf16
    unsigned int u = __float_as_uint(x);
    unsigned int r = (u + 0x7FFFu + ((u >> 16) & 1u)) >> 16;
    return (unsigned short)r;
}

// ---------------------------------------------------------------------------
// G[row][c] = X[row,:] . W[c,:] + bias1[c] + bias2[c]   (layer-0 input gates)
// ---------------------------------------------------------------------------
template<int K, bool CONCAT>
__global__ __launch_bounds__(256) void gemm_ih_kernel(
    const float* __restrict__ Xa, const float* __restrict__ Xb,
    const float* __restrict__ W,
    const float* __restrict__ bias1, const float* __restrict__ bias2,
    float* __restrict__ Gout)
{
    __shared__ __align__(16) float Ws[64*68];
    __shared__ __align__(16) float Xs[64*68];
    const int tid   = threadIdx.x;
    const int chunk = blockIdx.x & 7;
    const int rtile = blockIdx.x >> 3;
    const int row0  = rtile * 64;
    const int c0    = chunk * 64;
    const int cgrp  = tid & 15;
    const int rgrp  = tid >> 4;

    float acc[4][4] = {};

    if constexpr (CONCAT) {
        for (int e = tid; e < 64*65; e += 256) {
            int c = e / 65, kk = e - c*65;
            Ws[c*68 + kk] = W[(size_t)(c0 + c)*65 + kk];
        }
        for (int e = tid; e < 64*65; e += 256) {
            int r = e / 65, kk = e - r*65;
            Xs[r*68 + kk] = (kk < 64) ? Xa[(size_t)(row0 + r)*64 + kk]
                                      : Xb[row0 + r];
        }
        __syncthreads();
        #pragma unroll 4
        for (int kq = 0; kq < 16; ++kq) {
            const int kk = kq*4;
            float4 xv[4], wv[4];
            #pragma unroll
            for (int rr = 0; rr < 4; ++rr)
                xv[rr] = *(const float4*)&Xs[(rgrp*4 + rr)*68 + kk];
            #pragma unroll
            for (int i = 0; i < 4; ++i)
                wv[i] = *(const float4*)&Ws[(cgrp + 16*i)*68 + kk];
            #pragma unroll
            for (int rr = 0; rr < 4; ++rr)
                #pragma unroll
                for (int i = 0; i < 4; ++i) {
                    float s = acc[rr][i];
                    s = fmaf(xv[rr].x, wv[i].x, s);
                    s = fmaf(xv[rr].y, wv[i].y, s);
                    s = fmaf(xv[rr].z, wv[i].z, s);
                    s = fmaf(xv[rr].w, wv[i].w, s);
                    acc[rr][i] = s;
                }
        }
        {
            float xv[4], wv[4];
            #pragma unroll
            for (int rr = 0; rr < 4; ++rr) xv[rr] = Xs[(rgrp*4 + rr)*68 + 64];
            #pragma unroll
            for (int i = 0; i < 4; ++i)  wv[i]  = Ws[(cgrp + 16*i)*68 + 64];
            #pragma unroll
            for (int rr = 0; rr < 4; ++rr)
                #pragma unroll
                for (int i = 0; i < 4; ++i)
                    acc[rr][i] = fmaf(xv[rr], wv[i], acc[rr][i]);
        }
    } else {
        for (int k0 = 0; k0 < K; k0 += 64) {
            for (int e = tid; e < 64*16; e += 256) {
                int c = e >> 4, q = e & 15;
                *(float4*)&Ws[c*68 + q*4] =
                    *(const float4*)&W[(size_t)(c0 + c)*K + k0 + q*4];
            }
            for (int e = tid; e < 64*16; e += 256) {
                int r = e >> 4, q = e & 15;
                *(float4*)&Xs[r*68 + q*4] =
                    *(const float4*)&Xa[(size_t)(row0 + r)*K + k0 + q*4];
            }
            __syncthreads();
            #pragma unroll 4
            for (int kq = 0; kq < 16; ++kq) {
                const int kk = kq*4;
                float4 xv[4], wv[4];
                #pragma unroll
                for (int rr = 0; rr < 4; ++rr)
                    xv[rr] = *(const float4*)&Xs[(rgrp*4 + rr)*68 + kk];
                #pragma unroll
                for (int i = 0; i < 4; ++i)
                    wv[i] = *(const float4*)&Ws[(cgrp + 16*i)*68 + kk];
                #pragma unroll
                for (int rr = 0; rr < 4; ++rr)
                    #pragma unroll
                    for (int i = 0; i < 4; ++i) {
                        float s = acc[rr][i];
                        s = fmaf(xv[rr].x, wv[i].x, s);
                        s = fmaf(xv[rr].y, wv[i].y, s);
                        s = fmaf(xv[rr].z, wv[i].z, s);
                        s = fmaf(xv[rr].w, wv[i].w, s);
                        acc[rr][i] = s;
                    }
            }
            __syncthreads();
        }
    }

    #pragma unroll
    for (int i = 0; i < 4; ++i) {
        const int c = c0 + cgrp + 16*i;
        const float bb = bias1[c] + bias2[c];
        #pragma unroll
        for (int rr = 0; rr < 4; ++rr) {
            const int r = row0 + rgrp*4 + rr;
            Gout[(size_t)r*512 + c] = acc[rr][i] + bb;
        }
    }
}

// ---------------------------------------------------------------------------
// FUSED two-layer MFMA LSTM. One batch element per block (256 blocks),
// 512 threads = 8 waves. Software pipeline: iteration t computes
//   layer0: s1[t]   = f(G0[t], Whh0 . s1[t-1])          (t < steps)
//   layer1: s2[t-1] = f([Wih1|Whh1].[s1[t-1]; s2[t-2]] + bias1, c2)  (t >= 1)
// Iterations t = 0..steps (steps+1 total). One barrier per iteration.
// Weight B-frags in registers: Whh0(64) + Wih1(64) + Whh1(64) = 192 VGPR bf16.
// A-frag regs REUSED between s1 and s2 reads (keeps regs ~<=250).
// Gate math on kg==0 lanes (acc is row-uniform; every lane holds 4 tiles'
// values for its column). G0 prefetched 1 step ahead. Raw lgkmcnt+barrier
// keeps G loads / h2 stores in flight across iterations.
// Eliminates: gemm128 kernel, G1 traffic, s1_all stores (r9 -> r10).
// ---------------------------------------------------------------------------
__global__ __launch_bounds__(512, 2) void lstm_fused_kernel(
    const float* __restrict__ G,       // (steps*BB, 512) layer-0 gates + biases
    const float* __restrict__ wh0,     // Whh0 (512,128)
    const float* __restrict__ wi1,     // Wih1 (512,128)
    const float* __restrict__ wh1,     // Whh1 (512,128)
    const float* __restrict__ bi1,     // b_ih1 (512)
    const float* __restrict__ bh1,     // b_hh1 (512)
    float* __restrict__ h_state,       // (2*BB,128): layer0 then layer1
    float* __restrict__ c_state,       // (2*BB,128)
    float* __restrict__ h2_all,        // (steps*BB,128)
    int steps)
{
    const int tid  = threadIdx.x;
    const int wave = tid >> 6;
    const int lane = tid & 63;
    const int b    = blockIdx.x;
    const int col  = lane & 15;
    const int kg   = lane >> 4;
    const int m    = wave*16 + col;

    __shared__ __align__(16) unsigned short s1_bf[2][128];
    __shared__ __align__(16) unsigned short s2_bf[2][128];

    short8 bf0[4][4], bf1a[4][4], bf1b[4][4];   // 192 VGPR bf16 frags
    {
        #pragma unroll
        for (int tn = 0; tn < 4; ++tn) {
            const int j = tn*128 + m;
            #pragma unroll
            for (int ks = 0; ks < 4; ++ks) {
                const int ko = ks*32 + kg*8;
                const float* s0 = wh0 + (size_t)j*128 + ko;
                const float* sa = wi1 + (size_t)j*128 + ko;
                const float* sb = wh1 + (size_t)j*128 + ko;
                short8 v0, va, vb;
                #pragma unroll
                for (int i = 0; i < 8; ++i) {
                    v0[i] = (short)f2bf(s0[i]);
                    va[i] = (short)f2bf(sa[i]);
                    vb[i] = (short)f2bf(sb[i]);
                }
                bf0[tn][ks] = v0; bf1a[tn][ks] = va; bf1b[tn][ks] = vb;
            }
        }
    }

    float c1 = 0.f, c2 = 0.f, s1_last = 0.f, s2_last = 0.f;
    f32x4 bias1v = {0.f,0.f,0.f,0.f};
    const size_t goff0 = (size_t)b*512 + m;
    f32x4 gA = {0.f,0.f,0.f,0.f};
    if (kg == 0) {
        s1_last = h_state[b*128 + m];
        c1      = c_state[b*128 + m];
        s2_last = h_state[(BB + b)*128 + m];
        c2      = c_state[(BB + b)*128 + m];
        s1_bf[0][m] = f2bf(s1_last);
        {
            unsigned short s2b = f2bf(s2_last);
            s2_bf[0][m] = s2b;  s2_bf[1][m] = s2b;
        }
        #pragma unroll
        for (int tn = 0; tn < 4; ++tn)
            bias1v[tn] = bi1[tn*128 + m] + bh1[tn*128 + m];
        gA[0] = G[goff0];       gA[1] = G[goff0 + 128];
        gA[2] = G[goff0 + 256]; gA[3] = G[goff0 + 384];
    }
    asm volatile("s_waitcnt lgkmcnt(0)" ::: "memory");
    __builtin_amdgcn_s_barrier();
    __builtin_amdgcn_sched_barrier(0);

    #define FSTEP(T_, RB, WB)                                                   \
    {                                                                           \
        /* A-frags: s1[T_-1] (shared by layer0 + layer1 ih-part) */             \
        short8 af0 = *(const short8*)&s1_bf[RB][0*32 + kg*8];                   \
        short8 af1 = *(const short8*)&s1_bf[RB][1*32 + kg*8];                   \
        short8 af2 = *(const short8*)&s1_bf[RB][2*32 + kg*8];                   \
        short8 af3 = *(const short8*)&s1_bf[RB][3*32 + kg*8];                   \
        f32x4 g4 = gA;                   /* G0 row T_ (captured pre-reload) */  \
        if (kg == 0 && (T_) + 1 < steps) {                                      \
            const size_t of = (size_t)((T_) + 1)*BB*512 + goff0;                \
            f32x4 gg;                                                           \
            gg[0] = G[of];       gg[1] = G[of + 128];                           \
            gg[2] = G[of + 256]; gg[3] = G[of + 384];                           \
            gA = gg;                                                            \
        }                                                                       \
        f32x4 a0 = {0.f,0.f,0.f,0.f}, a1 = a0, a2 = a0, a3 = a0;                \
        f32x4 b0 = {0.f,0.f,0.f,0.f}, b1 = b0, b2 = b0, b3 = b0;                \
        _Pragma("unroll")                                                       \
        for (int ks = 0; ks < 4; ++ks) {                                        \
            short8 af = (ks==0)?af0:(ks==1)?af1:(ks==2)?af2:af3;                \
            a0 = __builtin_amdgcn_mfma_f32_16x16x32_bf16(af, bf0[0][ks], a0,0,0,0); \
            a1 = __builtin_amdgcn_mfma_f32_16x16x32_bf16(af, bf0[1][ks], a1,0,0,0); \
            a2 = __builtin_amdgcn_mfma_f32_16x16x32_bf16(af, bf0[2][ks], a2,0,0,0); \
            a3 = __builtin_amdgcn_mfma_f32_16x16x32_bf16(af, bf0[3][ks], a3,0,0,0); \
            b0 = __builtin_amdgcn_mfma_f32_16x16x32_bf16(af, bf1a[0][ks], b0,0,0,0);\
            b1 = __builtin_amdgcn_mfma_f32_16x16x32_bf16(af, bf1a[1][ks], b1,0,0,0);\
            b2 = __builtin_amdgcn_mfma_f32_16x16x32_bf16(af, bf1a[2][ks], b2,0,0,0);\
            b3 = __builtin_amdgcn_mfma_f32_16x16x32_bf16(af, bf1a[3][ks], b3,0,0,0);\
        }                                                                       \
        if (kg == 0 && (T_) < steps) {   /* layer0 gates -> s1[T_] */           \
            float iv = sigmoid_f(a0[0] + g4[0]);                                \
            float fv = sigmoid_f(a1[0] + g4[1]);                                \
            float gv = tanh_f   (a2[0] + g4[2]);                                \
            float ov = sigmoid_f(a3[0] + g4[3]);                                \
            c1 = fmaf(fv, c1, iv*gv);                                           \
            float hv = ov * tanh_f(c1);                                         \
            s1_last = hv;                                                       \
            s1_bf[WB][m] = f2bf(hv);                                            \
        }                                                                       \
        /* reuse af regs for s2[T_-2] frags */                                  \
        af0 = *(const short8*)&s2_bf[RB][0*32 + kg*8];                          \
        af1 = *(const short8*)&s2_bf[RB][1*32 + kg*8];                          \
        af2 = *(const short8*)&s2_bf[RB][2*32 + kg*8];                          \
        af3 = *(const short8*)&s2_bf[RB][3*32 + kg*8];                          \
        _Pragma("unroll")                                                       \
        for (int ks = 0; ks < 4; ++ks) {                                        \
            short8 af = (ks==0)?af0:(ks==1)?af1:(ks==2)?af2:af3;                \
            b0 = __builtin_amdgcn_mfma_f32_16x16x32_bf16(af, bf1b[0][ks], b0,0,0,0);\
            b1 = __builtin_amdgcn_mfma_f32_16x16x32_bf16(af, bf1b[1][ks], b1,0,0,0);\
            b2 = __builtin_amdgcn_mfma_f32_16x16x32_bf16(af, bf1b[2][ks], b2,0,0,0);\
            b3 = __builtin_amdgcn_mfma_f32_16x16x32_bf16(af, bf1b[3][ks], b3,0,0,0);\
        }                                                                       \
        if (kg == 0 && (T_) >= 1) {      /* layer1 gates -> s2[T_-1] */         \
            float iv = sigmoid_f(b0[0] + bias1v[0]);                            \
            float fv = sigmoid_f(b1[0] + bias1v[1]);                            \
            float gv = tanh_f   (b2[0] + bias1v[2]);                            \
            float ov = sigmoid_f(b3[0] + bias1v[3]);                            \
            c2 = fmaf(fv, c2, iv*gv);                                           \
            float hv = ov * tanh_f(c2);                                         \
            s2_last = hv;                                                       \
            s2_bf[WB][m] = f2bf(hv);                                            \
            h2_all[((size_t)((T_) - 1)*BB + b)*128 + m] = hv;                   \
        }                                                                       \
        asm volatile("s_waitcnt lgkmcnt(0)" ::: "memory");                      \
        __builtin_amdgcn_s_barrier();                                           \
        __builtin_amdgcn_sched_barrier(0);                                      \
    }

    FSTEP(0, 0, 1);
    for (int t = 1; t < steps; t += 2) {
        FSTEP(t,     1, 0);
        FSTEP(t + 1, 0, 1);
    }
    #undef FSTEP

    if (kg == 0) {
        h_state[b*128 + m]        = s1_last;
        c_state[b*128 + m]        = c1;
        h_state[(BB + b)*128 + m] = s2_last;
        c_state[(BB + b)*128 + m] = c2;
    }
}

// ---------------------------------------------------------------------------
__global__ __launch_bounds__(256) void init_state_kernel(
    const float* __restrict__ h0, const float* __restrict__ c0,
    float* __restrict__ h_state, float* __restrict__ c_state)
{
    const int idx = blockIdx.x*256 + threadIdx.x;
    h_state[idx] = h0[idx];
    c_state[idx] = c0[idx];
}

// ---------------------------------------------------------------------------
// Goal decoder: latents(64) -> 64 relu -> 32 ; goals + log_prob_goals
// ---------------------------------------------------------------------------
__global__ __launch_bounds__(256) void dec_goal_kernel(
    const float* __restrict__ h2,
    const float* __restrict__ geps,
    const float* __restrict__ w1, const float* __restrict__ b1,
    const float* __restrict__ w2, const float* __restrict__ b2,
    float* __restrict__ out_goals, float* __restrict__ out_lpg)
{
    __shared__ float W1[64*64];
    __shared__ float W2[32*64];
    __shared__ float B1[64];
    __shared__ float B2[32];
    const int tid = threadIdx.x;
    for (int e = tid; e < 64*64; e += 256) W1[e] = w1[e];
    for (int e = tid; e < 32*64; e += 256) W2[e] = w2[e];
    if (tid < 64) B1[tid] = b1[tid];
    if (tid < 32) B2[tid] = b2[tid];
    __syncthreads();

    const size_t row = (size_t)blockIdx.x*256 + tid;
    const float* xr = h2 + row*128;

    float hid[64];
    #pragma unroll
    for (int jj = 0; jj < 64; ++jj) hid[jj] = B1[jj];
    for (int k = 0; k < 64; k += 4) {
        float4 xv = *(const float4*)(xr + k);
        #pragma unroll
        for (int jj = 0; jj < 64; ++jj) {
            float s = hid[jj];
            s = fmaf(W1[jj*64 + k],     xv.x, s);
            s = fmaf(W1[jj*64 + k + 1], xv.y, s);
            s = fmaf(W1[jj*64 + k + 2], xv.z, s);
            s = fmaf(W1[jj*64 + k + 3], xv.w, s);
            hid[jj] = s;
        }
    }
    #pragma unroll
    for (int jj = 0; jj < 64; ++jj) hid[jj] = fmaxf(hid[jj], 0.f);

    float gm[16];
    #pragma unroll
    for (int jj = 0; jj < 16; ++jj) {
        float s = B2[jj];
        #pragma unroll
        for (int k = 0; k < 64; ++k) s = fmaf(W2[jj*64 + k], hid[k], s);
        gm[jj] = 100.f * tanh_f(0.001f * s);
    }
    float ge[16];
    #pragma unroll
    for (int d = 0; d < 16; d += 4) {
        float4 v = *(const float4*)(geps + row*16 + d);
        ge[d]=v.x; ge[d+1]=v.y; ge[d+2]=v.z; ge[d+3]=v.w;
    }
    float lsum = 0.f;
    float goalv[16];
    #pragma unroll
    for (int jj = 0; jj < 16; ++jj) {
        float s = B2[16 + jj];
        #pragma unroll
        for (int k = 0; k < 64; ++k) s = fmaf(W2[(16+jj)*64 + k], hid[k], s);
        float gs   = tanh_f(s);
        float gvar = fmaf(gs, gs, 0.001f);
        float goal = fmaf(sqrtf(gvar), ge[jj], gm[jj]);
        goalv[jj] = goal;
        float dd = goal - gm[jj];
        lsum += dd*dd/gvar + __logf(gvar);
    }
    #pragma unroll
    for (int d = 0; d < 16; d += 4) {
        float4 v = make_float4(goalv[d], goalv[d+1], goalv[d+2], goalv[d+3]);
        *(float4*)(out_goals + row*16 + d) = v;
    }
    out_lpg[row] = -0.5f*(lsum + 16.f*LOG2PI);
}

// ---------------------------------------------------------------------------
// Action + value decoder: goal_obs(80) -> [ad: 80 relu -> 16], [vd: 80 relu -> 1]
// ---------------------------------------------------------------------------
__global__ __launch_bounds__(256) void dec_av_kernel(
    const float* __restrict__ goals,
    const float* __restrict__ obs,
    const float* __restrict__ aeps,
    const float* __restrict__ aw1, const float* __restrict__ ab1,
    const float* __restrict__ aw2, const float* __restrict__ ab2,
    const float* __restrict__ vw1, const float* __restrict__ vb1,
    const float* __restrict__ vw2, const float* __restrict__ vb2,
    float* __restrict__ out_actions, float* __restrict__ out_lpa,
    float* __restrict__ out_values)
{
    __shared__ float AW1[80*80];
    __shared__ float VW1[80*80];
    __shared__ float AW2[16*80];
    __shared__ float VW2[80];
    __shared__ float AB1[80];
    __shared__ float VB1[80];
    __shared__ float AB2[16];
    const int tid = threadIdx.x;
    for (int e = tid; e < 80*80; e += 256) { AW1[e] = aw1[e]; VW1[e] = vw1[e]; }
    for (int e = tid; e < 16*80; e += 256) AW2[e] = aw2[e];
    if (tid < 80) { VW2[tid] = vw2[tid]; AB1[tid] = ab1[tid]; VB1[tid] = vb1[tid]; }
    if (tid < 16) AB2[tid] = ab2[tid];
    __syncthreads();

    const size_t row = (size_t)blockIdx.x*256 + tid;

    float hid[80];
    #pragma unroll
    for (int jj = 0; jj < 80; ++jj) hid[jj] = AB1[jj];
    for (int k = 0; k < 80; k += 4) {
        float4 xv;
        if (k < 16) xv = *(const float4*)(goals + row*16 + k);
        else        xv = *(const float4*)(obs + row*64 + (k - 16));
        #pragma unroll
        for (int jj = 0; jj < 80; ++jj) {
            float s = hid[jj];
            s = fmaf(AW1[jj*80 + k],     xv.x, s);
            s = fmaf(AW1[jj*80 + k + 1], xv.y, s);
            s = fmaf(AW1[jj*80 + k + 2], xv.z, s);
            s = fmaf(AW1[jj*80 + k + 3], xv.w, s);
            hid[jj] = s;
        }
    }
    #pragma unroll
    for (int jj = 0; jj < 80; ++jj) hid[jj] = fmaxf(hid[jj], 0.f);

    float am[8], asd[8];
    #pragma unroll
    for (int jj = 0; jj < 8; ++jj) {
        float s = AB2[jj];
        #pragma unroll
        for (int k = 0; k < 80; ++k) s = fmaf(AW2[jj*80 + k], hid[k], s);
        am[jj] = s;
    }
    #pragma unroll
    for (int jj = 0; jj < 8; ++jj) {
        float s = AB2[8 + jj];
        #pragma unroll
        for (int k = 0; k < 80; ++k) s = fmaf(AW2[(8+jj)*80 + k], hid[k], s);
        asd[jj] = s;
    }

    float ae[8];
    #pragma unroll
    for (int d = 0; d < 8; d += 4) {
        float4 v = *(const float4*)(aeps + row*8 + d);
        ae[d]=v.x; ae[d+1]=v.y; ae[d+2]=v.z; ae[d+3]=v.w;
    }
    float lsum = 0.f;
    float actv[8];
    #pragma unroll
    for (int d = 0; d < 8; ++d) {
        float avar = fmaf(asd[d], asd[d], 0.001f);
        float act  = fmaf(sqrtf(avar), ae[d], am[d]);
        actv[d] = act;
        float dd = act - am[d];
        lsum += dd*dd/avar + __logf(avar);
    }
    #pragma unroll
    for (int d = 0; d < 8; d += 4) {
        float4 v = make_float4(actv[d], actv[d+1], actv[d+2], actv[d+3]);
        *(float4*)(out_actions + row*8 + d) = v;
    }
    out_lpa[row] = -0.5f*(lsum + 8.f*LOG2PI);

    float vh[80];
    #pragma unroll
    for (int jj = 0; jj < 80; ++jj) vh[jj] = VB1[jj];
    for (int k = 0; k < 80; k += 4) {
        float4 xv;
        if (k < 16) xv = *(const float4*)(goals + row*16 + k);
        else        xv = *(const float4*)(obs + row*64 + (k - 16));
        #pragma unroll
        for (int jj = 0; jj < 80; ++jj) {
            float s = vh[jj];
            s = fmaf(VW1[jj*80 + k],     xv.x, s);
            s = fmaf(VW1[jj*80 + k + 1], xv.y, s);
            s = fmaf(VW1[jj*80 + k + 2], xv.z, s);
            s = fmaf(VW1[jj*80 + k + 3], xv.w, s);
            vh[jj] = s;
        }
    }
    float v = vb2[0];
    #pragma unroll
    for (int jj = 0; jj < 80; ++jj) v = fmaf(VW2[jj], fmaxf(vh[jj], 0.f), v);
    out_values[row] = v;
}

// ---------------------------------------------------------------------------
// lp decoder: full_lat_obs(192) -> 192 relu -> 1.
// ---------------------------------------------------------------------------
__global__ __launch_bounds__(256) void dec_lpv_kernel(
    const float* __restrict__ h2,
    const float* __restrict__ obs,
    const float* __restrict__ w1, const float* __restrict__ b1,
    const float* __restrict__ w2, const float* __restrict__ b2,
    float* __restrict__ out_lpv)
{
    __shared__ __align__(16) float W1s[64*192];
    __shared__ float B1[192];
    __shared__ float W2[192];
    const int tid = threadIdx.x;
    const int l = tid & 3;
    const size_t item = (size_t)blockIdx.x*64 + (tid >> 2);
    if (tid < 192) { B1[tid] = b1[tid]; W2[tid] = w2[tid]; }

    float x[48];
    #pragma unroll
    for (int q = 0; q < 12; ++q) {
        int gk = l*48 + q*4;
        float4 v;
        if (gk < 128) v = *(const float4*)(h2 + item*128 + gk);
        else          v = *(const float4*)(obs + item*64 + (gk - 128));
        x[q*4]=v.x; x[q*4+1]=v.y; x[q*4+2]=v.z; x[q*4+3]=v.w;
    }

    float acc = 0.f;
    for (int j0 = 0; j0 < 192; j0 += 64) {
        __syncthreads();
        for (int e = tid; e < 64*48; e += 256) {
            int rr = e / 48, q = e - rr*48;
            *(float4*)&W1s[rr*192 + q*4] =
                *(const float4*)&w1[(size_t)(j0 + rr)*192 + q*4];
        }
        __syncthreads();
        for (int jj = 0; jj < 64; ++jj) {
            const float* wr = W1s + jj*192 + l*48;
            float p = 0.f;
            #pragma unroll
            for (int q = 0; q < 12; ++q) {
                float4 wv = *(const float4*)(wr + q*4);
                p = fmaf(wv.x, x[q*4],     p);
                p = fmaf(wv.y, x[q*4 + 1], p);
                p = fmaf(wv.z, x[q*4 + 2], p);
                p = fmaf(wv.w, x[q*4 + 3], p);
            }
            p += __shfl_xor(p, 1);
            p += __shfl_xor(p, 2);
            float h = fmaxf(p + B1[j0 + jj], 0.f);
            acc = fmaf(W2[j0 + jj], h, acc);
        }
    }
    if (l == 0) out_lpv[item] = acc + b2[0];
}

// ---------------------------------------------------------------------------
extern "C" void kernel_launch(void* const* d_in, const int* in_sizes, int n_in,
                              void* d_out, int out_size, void* d_ws, size_t ws_size,
                              hipStream_t stream)
{
    (void)in_sizes; (void)n_in; (void)out_size;

    const float* obs    = (const float*)d_in[0];
    const float* lps    = (const float*)d_in[1];
    const float* geps   = (const float*)d_in[2];
    const float* aeps   = (const float*)d_in[3];
    const float* h0     = (const float*)d_in[4];
    const float* c0     = (const float*)d_in[5];
    const float* w_ih0  = (const float*)d_in[6];
    const float* b_ih0  = (const float*)d_in[7];
    const float* w_hh0  = (const float*)d_in[8];
    const float* b_hh0  = (const float*)d_in[9];
    const float* w_ih1  = (const float*)d_in[10];
    const float* b_ih1  = (const float*)d_in[11];
    const float* w_hh1  = (const float*)d_in[12];
    const float* b_hh1  = (const float*)d_in[13];
    const float* gd_w1  = (const float*)d_in[14];
    const float* gd_b1  = (const float*)d_in[15];
    const float* gd_w2  = (const float*)d_in[16];
    const float* gd_b2  = (const float*)d_in[17];
    const float* ad_w1  = (const float*)d_in[18];
    const float* ad_b1  = (const float*)d_in[19];
    const float* ad_w2  = (const float*)d_in[20];
    const float* ad_b2  = (const float*)d_in[21];
    const float* vd_w1  = (const float*)d_in[22];
    const float* vd_b1  = (const float*)d_in[23];
    const float* vd_w2  = (const float*)d_in[24];
    const float* vd_b2  = (const float*)d_in[25];
    const float* lpd_w1 = (const float*)d_in[26];
    const float* lpd_b1 = (const float*)d_in[27];
    const float* lpd_w2 = (const float*)d_in[28];
    const float* lpd_b2 = (const float*)d_in[29];

    float* out         = (float*)d_out;
    float* out_actions = out;                 // (T,B,8)
    float* out_lpa     = out + 2097152;       // (T,B)
    float* out_goals   = out + 2359296;       // (T,B,16)
    float* out_lpg     = out + 6553600;       // (T,B)
    float* out_values  = out + 6815744;       // (T,B,1)
    float* out_lpv     = out + 7077888;       // (T,B,1)

    // --- adaptive time-chunking (fused kernel: only G + h2 per chunk) ---
    const size_t STATE_ELEMS = 2ull * BB * 128;            // per h or c
    const size_t state_bytes = 2ull * STATE_ELEMS * 4;     // h + c
    int C = 0;
    for (int c = TT; c >= 8; c >>= 1) {
        size_t need = (size_t)c * BB * (512 + 128) * 4 + state_bytes;
        if (need <= ws_size) { C = c; break; }
    }
    if (C == 0) return;
    const int nchunks = TT / C;

    float* Gc      = (float*)d_ws;
    float* h2c     = Gc  + (size_t)C * BB * 512;
    float* h_state = h2c + (size_t)C * BB * 128;
    float* c_state = h_state + STATE_ELEMS;

    const dim3 blk(256);
    init_state_kernel<<<dim3((int)(STATE_ELEMS/256)), blk, 0, stream>>>(
        h0, c0, h_state, c_state);

    for (int ch = 0; ch < nchunks; ++ch) {
        const size_t crow0 = (size_t)ch * C * BB;
        const int rows = C * BB;

        gemm_ih_kernel<65, true><<<dim3((rows/64)*8), blk, 0, stream>>>(
            obs + crow0*64, lps + crow0, w_ih0, b_ih0, b_hh0, Gc);

        lstm_fused_kernel<<<dim3(BB), dim3(512), 0, stream>>>(
            Gc, w_hh0, w_ih1, w_hh1, b_ih1, b_hh1,
            h_state, c_state, h2c, C);

        dec_goal_kernel<<<dim3(rows/256), blk, 0, stream>>>(
            h2c, geps + crow0*16, gd_w1, gd_b1, gd_w2, gd_b2,
            out_goals + crow0*16, out_lpg + crow0);

        dec_av_kernel<<<dim3(rows/256), blk, 0, stream>>>(
            out_goals + crow0*16, obs + crow0*64, aeps + crow0*8,
            ad_w1, ad_b1, ad_w2, ad_b2, vd_w1, vd_b1, vd_w2, vd_b2,
            out_actions + crow0*8, out_lpa + crow0, out_values + crow0);

        dec_lpv_kernel<<<dim3(rows/64), blk, 0, stream>>>(
            h2c, obs + crow0*64, lpd_w1, lpd_b1, lpd_w2, lpd_b2,
            out_lpv + crow0);
    }
}

// Round 11
// 2376.732 us; speedup vs baseline: 1.7097x; 1.7097x over previous
//
#include <hip/hip_runtime.h>
#include <hip/hip_bf16.h>
#include <math.h>

#define TT 1024
#define BB 256
#define LOG2PI 1.8378770664093453f

typedef short short8 __attribute__((ext_vector_type(8)));
typedef float f32x4  __attribute__((ext_vector_type(4)));

__device__ __forceinline__ float sigmoid_f(float x) {
    return 1.f / (1.f + __expf(-x));
}
__device__ __forceinline__ float tanh_f(float x) {
    return 1.f - 2.f / (__expf(2.f*x) + 1.f);
}
__device__ __forceinline__ unsigned short f2bf(float x) {   // RNE fp32->bf16
    unsigned int u = __float_as_uint(x);
    unsigned int r = (u + 0x7FFFu + ((u >> 16) & 1u)) >> 16;
    return (unsigned short)r;
}

#define MF(acc, a, bfr) acc = __builtin_amdgcn_mfma_f32_16x16x32_bf16((a), (bfr), (acc), 0, 0, 0)

// ---------------------------------------------------------------------------
// obs (T*B*64 f32) -> bf16 copy (one-time; feeds lstm0's A-fragments)
// ---------------------------------------------------------------------------
__global__ __launch_bounds__(256) void cvt_bf16_kernel(
    const float* __restrict__ in, unsigned short* __restrict__ out)
{
    const int i = blockIdx.x*256 + threadIdx.x;   // 8 floats per thread
    const float4 a = ((const float4*)in)[2*i];
    const float4 b = ((const float4*)in)[2*i + 1];
    short8 v;
    v[0]=(short)f2bf(a.x); v[1]=(short)f2bf(a.y);
    v[2]=(short)f2bf(a.z); v[3]=(short)f2bf(a.w);
    v[4]=(short)f2bf(b.x); v[5]=(short)f2bf(b.y);
    v[6]=(short)f2bf(b.z); v[7]=(short)f2bf(b.w);
    ((short8*)out)[i] = v;
}

// ---------------------------------------------------------------------------
__global__ __launch_bounds__(256) void init_state_kernel(
    const float* __restrict__ h0, const float* __restrict__ c0,
    float* __restrict__ h_state, float* __restrict__ c_state)
{
    const int idx = blockIdx.x*256 + threadIdx.x;
    h_state[idx] = h0[idx];
    c_state[idx] = c0[idx];
}

// ---------------------------------------------------------------------------
// Layer-0 fused LSTM: gates = Whh0.s1 (MFMA, 4 kslices) + Wih0[:, :64].x
// (MFMA, 2 kslices, x bf16 from global per-lane, prefetched) +
// wih0[:,64]*lps (scalar fp32) + biases. One batch element per block,
// 512 threads = 8 waves; tile tn = gate block; kg==0 lanes do gate math
// lane-locally (row-uniform MFMA output). Single raw barrier per step.
// Weight frags: 96 regs. Writes h1 as bf16 (consumed by lstm1).
// ---------------------------------------------------------------------------
__global__ __launch_bounds__(512, 2) void lstm0_kernel(
    const unsigned short* __restrict__ xb,   // (steps*BB,64) bf16
    const float* __restrict__ lps,           // (steps*BB) f32
    const float* __restrict__ wi0,           // (512,65)
    const float* __restrict__ wh0,           // (512,128)
    const float* __restrict__ bi0, const float* __restrict__ bh0,
    float* __restrict__ h_state, float* __restrict__ c_state,  // (BB,128) L0
    unsigned short* __restrict__ h1_all,     // (steps*BB,128) bf16
    int steps)
{
    const int tid  = threadIdx.x;
    const int wave = tid >> 6;
    const int lane = tid & 63;
    const int b    = blockIdx.x;
    const int col  = lane & 15;
    const int kg   = lane >> 4;
    const int m    = wave*16 + col;

    __shared__ __align__(16) unsigned short s1_bf[2][128];

    short8 whf[4][4];   // Whh0 frags (64 regs)
    short8 wxf[4][2];   // Wih0 k<64 frags (32 regs)
    f32x4 wc64, bias4;
    #pragma unroll
    for (int tn = 0; tn < 4; ++tn) {
        const int j = tn*128 + m;
        #pragma unroll
        for (int ks = 0; ks < 4; ++ks) {
            const float* s = wh0 + (size_t)j*128 + ks*32 + kg*8;
            short8 v;
            #pragma unroll
            for (int i = 0; i < 8; ++i) v[i] = (short)f2bf(s[i]);
            whf[tn][ks] = v;
        }
        #pragma unroll
        for (int ks = 0; ks < 2; ++ks) {
            const float* s = wi0 + (size_t)j*65 + ks*32 + kg*8;
            short8 v;
            #pragma unroll
            for (int i = 0; i < 8; ++i) v[i] = (short)f2bf(s[i]);
            wxf[tn][ks] = v;
        }
        wc64[tn]  = wi0[(size_t)j*65 + 64];
        bias4[tn] = bi0[j] + bh0[j];
    }

    float c1 = 0.f, s1l = 0.f;
    if (kg == 0) {
        s1l = h_state[b*128 + m];
        c1  = c_state[b*128 + m];
        s1_bf[0][m] = f2bf(s1l);
    }
    // x / lps prefetch (pointer-incremental; xp points at row being loaded)
    const unsigned short* xp = xb + (size_t)b*64 + kg*8;
    const float* lpp = lps + b;
    short8 xA0 = *(const short8*)(xp);
    short8 xA1 = *(const short8*)(xp + 32);
    float  lpA = *lpp;
    xp  += (size_t)BB*64;   // -> t=1
    lpp += BB;
    unsigned short* h1p = h1_all + (size_t)b*128 + m;

    asm volatile("s_waitcnt lgkmcnt(0)" ::: "memory");
    __builtin_amdgcn_s_barrier();
    __builtin_amdgcn_sched_barrier(0);

    #define STEP0(T_, RB, WB)                                                   \
    {                                                                           \
        short8 af0 = *(const short8*)&s1_bf[RB][0*32 + kg*8];                   \
        short8 af1 = *(const short8*)&s1_bf[RB][1*32 + kg*8];                   \
        short8 af2 = *(const short8*)&s1_bf[RB][2*32 + kg*8];                   \
        short8 af3 = *(const short8*)&s1_bf[RB][3*32 + kg*8];                   \
        short8 xu0 = xA0, xu1 = xA1;  float lpu = lpA;   /* capture first */    \
        if ((T_) + 1 < steps) {                                                 \
            xA0 = *(const short8*)(xp);                                         \
            xA1 = *(const short8*)(xp + 32);                                    \
            lpA = *lpp;                                                         \
        }                                                                       \
        xp += (size_t)BB*64;  lpp += BB;                                        \
        f32x4 a0 = {0.f,0.f,0.f,0.f}, a1 = a0, a2 = a0, a3 = a0;                \
        MF(a0, af0, whf[0][0]); MF(a1, af0, whf[1][0]);                         \
        MF(a2, af0, whf[2][0]); MF(a3, af0, whf[3][0]);                         \
        MF(a0, af1, whf[0][1]); MF(a1, af1, whf[1][1]);                         \
        MF(a2, af1, whf[2][1]); MF(a3, af1, whf[3][1]);                         \
        MF(a0, af2, whf[0][2]); MF(a1, af2, whf[1][2]);                         \
        MF(a2, af2, whf[2][2]); MF(a3, af2, whf[3][2]);                         \
        MF(a0, af3, whf[0][3]); MF(a1, af3, whf[1][3]);                         \
        MF(a2, af3, whf[2][3]); MF(a3, af3, whf[3][3]);                         \
        MF(a0, xu0, wxf[0][0]); MF(a1, xu0, wxf[1][0]);                         \
        MF(a2, xu0, wxf[2][0]); MF(a3, xu0, wxf[3][0]);                         \
        MF(a0, xu1, wxf[0][1]); MF(a1, xu1, wxf[1][1]);                         \
        MF(a2, xu1, wxf[2][1]); MF(a3, xu1, wxf[3][1]);                         \
        if (kg == 0) {                                                          \
            float gi = a0[0] + bias4[0] + wc64[0]*lpu;                          \
            float gf = a1[0] + bias4[1] + wc64[1]*lpu;                          \
            float gg = a2[0] + bias4[2] + wc64[2]*lpu;                          \
            float go = a3[0] + bias4[3] + wc64[3]*lpu;                          \
            float iv = sigmoid_f(gi);                                           \
            float fv = sigmoid_f(gf);                                           \
            float gv = tanh_f(gg);                                              \
            float ov = sigmoid_f(go);                                           \
            c1 = fmaf(fv, c1, iv*gv);                                           \
            float hv = ov * tanh_f(c1);                                         \
            s1l = hv;                                                           \
            unsigned short hb = f2bf(hv);                                       \
            s1_bf[WB][m] = hb;                                                  \
            *h1p = hb;                                                          \
        }                                                                       \
        h1p += (size_t)BB*128;                                                  \
        asm volatile("s_waitcnt lgkmcnt(0)" ::: "memory");                      \
        __builtin_amdgcn_s_barrier();                                           \
        __builtin_amdgcn_sched_barrier(0);                                      \
    }

    for (int t = 0; t < steps; t += 2) {
        STEP0(t,     0, 1);
        STEP0(t + 1, 1, 0);
    }
    #undef STEP0

    if (kg == 0) {
        h_state[b*128 + m] = s1l;
        c_state[b*128 + m] = c1;
    }
}

// ---------------------------------------------------------------------------
// Layer-1 fused LSTM: gates = Wih1.s1[t] (A-frags per-lane from h1_all bf16,
// prefetched 1 step) + Whh1.s2[t-1] (LDS dbuf) + biases. 128 weight frag regs.
// ---------------------------------------------------------------------------
__global__ __launch_bounds__(512, 2) void lstm1_kernel(
    const unsigned short* __restrict__ h1_all,   // (steps*BB,128) bf16
    const float* __restrict__ wi1, const float* __restrict__ wh1,  // (512,128)
    const float* __restrict__ bi1, const float* __restrict__ bh1,
    float* __restrict__ h_state, float* __restrict__ c_state,  // L1 slices
    float* __restrict__ h2_all,                  // (steps*BB,128) f32
    int steps)
{
    const int tid  = threadIdx.x;
    const int wave = tid >> 6;
    const int lane = tid & 63;
    const int b    = blockIdx.x;
    const int col  = lane & 15;
    const int kg   = lane >> 4;
    const int m    = wave*16 + col;

    __shared__ __align__(16) unsigned short s2_bf[2][128];

    short8 wif[4][4], whf[4][4];   // 128 regs
    f32x4 bias4;
    #pragma unroll
    for (int tn = 0; tn < 4; ++tn) {
        const int j = tn*128 + m;
        #pragma unroll
        for (int ks = 0; ks < 4; ++ks) {
            const int ko = ks*32 + kg*8;
            const float* sa = wi1 + (size_t)j*128 + ko;
            const float* sb = wh1 + (size_t)j*128 + ko;
            short8 va, vb;
            #pragma unroll
            for (int i = 0; i < 8; ++i) {
                va[i] = (short)f2bf(sa[i]);
                vb[i] = (short)f2bf(sb[i]);
            }
            wif[tn][ks] = va;  whf[tn][ks] = vb;
        }
        bias4[tn] = bi1[j] + bh1[j];
    }

    float c2 = 0.f, s2l = 0.f;
    if (kg == 0) {
        s2l = h_state[b*128 + m];
        c2  = c_state[b*128 + m];
        s2_bf[0][m] = f2bf(s2l);
    }
    // s1 prefetch (pointer-incremental)
    const unsigned short* sp = h1_all + (size_t)b*128 + kg*8;
    short8 sA0 = *(const short8*)(sp);
    short8 sA1 = *(const short8*)(sp + 32);
    short8 sA2 = *(const short8*)(sp + 64);
    short8 sA3 = *(const short8*)(sp + 96);
    sp += (size_t)BB*128;   // -> t=1
    float* h2p = h2_all + (size_t)b*128 + m;

    asm volatile("s_waitcnt lgkmcnt(0)" ::: "memory");
    __builtin_amdgcn_s_barrier();
    __builtin_amdgcn_sched_barrier(0);

    #define STEP1(T_, RB, WB)                                                   \
    {                                                                           \
        short8 xu0 = sA0, xu1 = sA1, xu2 = sA2, xu3 = sA3;  /* capture */       \
        if ((T_) + 1 < steps) {                                                 \
            sA0 = *(const short8*)(sp);                                         \
            sA1 = *(const short8*)(sp + 32);                                    \
            sA2 = *(const short8*)(sp + 64);                                    \
            sA3 = *(const short8*)(sp + 96);                                    \
        }                                                                       \
        sp += (size_t)BB*128;                                                   \
        short8 af0 = *(const short8*)&s2_bf[RB][0*32 + kg*8];                   \
        short8 af1 = *(const short8*)&s2_bf[RB][1*32 + kg*8];                   \
        short8 af2 = *(const short8*)&s2_bf[RB][2*32 + kg*8];                   \
        short8 af3 = *(const short8*)&s2_bf[RB][3*32 + kg*8];                   \
        f32x4 b0 = {0.f,0.f,0.f,0.f}, b1 = b0, b2 = b0, b3 = b0;                \
        MF(b0, xu0, wif[0][0]); MF(b1, xu0, wif[1][0]);                         \
        MF(b2, xu0, wif[2][0]); MF(b3, xu0, wif[3][0]);                         \
        MF(b0, xu1, wif[0][1]); MF(b1, xu1, wif[1][1]);                         \
        MF(b2, xu1, wif[2][1]); MF(b3, xu1, wif[3][1]);                         \
        MF(b0, xu2, wif[0][2]); MF(b1, xu2, wif[1][2]);                         \
        MF(b2, xu2, wif[2][2]); MF(b3, xu2, wif[3][2]);                         \
        MF(b0, xu3, wif[0][3]); MF(b1, xu3, wif[1][3]);                         \
        MF(b2, xu3, wif[2][3]); MF(b3, xu3, wif[3][3]);                         \
        MF(b0, af0, whf[0][0]); MF(b1, af0, whf[1][0]);                         \
        MF(b2, af0, whf[2][0]); MF(b3, af0, whf[3][0]);                         \
        MF(b0, af1, whf[0][1]); MF(b1, af1, whf[1][1]);                         \
        MF(b2, af1, whf[2][1]); MF(b3, af1, whf[3][1]);                         \
        MF(b0, af2, whf[0][2]); MF(b1, af2, whf[1][2]);                         \
        MF(b2, af2, whf[2][2]); MF(b3, af2, whf[3][2]);                         \
        MF(b0, af3, whf[0][3]); MF(b1, af3, whf[1][3]);                         \
        MF(b2, af3, whf[2][3]); MF(b3, af3, whf[3][3]);                         \
        if (kg == 0) {                                                          \
            float iv = sigmoid_f(b0[0] + bias4[0]);                             \
            float fv = sigmoid_f(b1[0] + bias4[1]);                             \
            float gv = tanh_f   (b2[0] + bias4[2]);                             \
            float ov = sigmoid_f(b3[0] + bias4[3]);                             \
            c2 = fmaf(fv, c2, iv*gv);                                           \
            float hv = ov * tanh_f(c2);                                         \
            s2l = hv;                                                           \
            s2_bf[WB][m] = f2bf(hv);                                            \
            *h2p = hv;                                                          \
        }                                                                       \
        h2p += (size_t)BB*128;                                                  \
        asm volatile("s_waitcnt lgkmcnt(0)" ::: "memory");                      \
        __builtin_amdgcn_s_barrier();                                           \
        __builtin_amdgcn_sched_barrier(0);                                      \
    }

    for (int t = 0; t < steps; t += 2) {
        STEP1(t,     0, 1);
        STEP1(t + 1, 1, 0);
    }
    #undef STEP1

    if (kg == 0) {
        h_state[b*128 + m] = s2l;
        c_state[b*128 + m] = c2;
    }
}

// ---------------------------------------------------------------------------
// Goal decoder: latents(64) -> 64 relu -> 32 ; goals + log_prob_goals
// ---------------------------------------------------------------------------
__global__ __launch_bounds__(256) void dec_goal_kernel(
    const float* __restrict__ h2,
    const float* __restrict__ geps,
    const float* __restrict__ w1, const float* __restrict__ b1,
    const float* __restrict__ w2, const float* __restrict__ b2,
    float* __restrict__ out_goals, float* __restrict__ out_lpg)
{
    __shared__ float W1[64*64];
    __shared__ float W2[32*64];
    __shared__ float B1[64];
    __shared__ float B2[32];
    const int tid = threadIdx.x;
    for (int e = tid; e < 64*64; e += 256) W1[e] = w1[e];
    for (int e = tid; e < 32*64; e += 256) W2[e] = w2[e];
    if (tid < 64) B1[tid] = b1[tid];
    if (tid < 32) B2[tid] = b2[tid];
    __syncthreads();

    const size_t row = (size_t)blockIdx.x*256 + tid;
    const float* xr = h2 + row*128;

    float hid[64];
    #pragma unroll
    for (int jj = 0; jj < 64; ++jj) hid[jj] = B1[jj];
    for (int k = 0; k < 64; k += 4) {
        float4 xv = *(const float4*)(xr + k);
        #pragma unroll
        for (int jj = 0; jj < 64; ++jj) {
            float s = hid[jj];
            s = fmaf(W1[jj*64 + k],     xv.x, s);
            s = fmaf(W1[jj*64 + k + 1], xv.y, s);
            s = fmaf(W1[jj*64 + k + 2], xv.z, s);
            s = fmaf(W1[jj*64 + k + 3], xv.w, s);
            hid[jj] = s;
        }
    }
    #pragma unroll
    for (int jj = 0; jj < 64; ++jj) hid[jj] = fmaxf(hid[jj], 0.f);

    float gm[16];
    #pragma unroll
    for (int jj = 0; jj < 16; ++jj) {
        float s = B2[jj];
        #pragma unroll
        for (int k = 0; k < 64; ++k) s = fmaf(W2[jj*64 + k], hid[k], s);
        gm[jj] = 100.f * tanh_f(0.001f * s);
    }
    float ge[16];
    #pragma unroll
    for (int d = 0; d < 16; d += 4) {
        float4 v = *(const float4*)(geps + row*16 + d);
        ge[d]=v.x; ge[d+1]=v.y; ge[d+2]=v.z; ge[d+3]=v.w;
    }
    float lsum = 0.f;
    float goalv[16];
    #pragma unroll
    for (int jj = 0; jj < 16; ++jj) {
        float s = B2[16 + jj];
        #pragma unroll
        for (int k = 0; k < 64; ++k) s = fmaf(W2[(16+jj)*64 + k], hid[k], s);
        float gs   = tanh_f(s);
        float gvar = fmaf(gs, gs, 0.001f);
        float goal = fmaf(sqrtf(gvar), ge[jj], gm[jj]);
        goalv[jj] = goal;
        float dd = goal - gm[jj];
        lsum += dd*dd/gvar + __logf(gvar);
    }
    #pragma unroll
    for (int d = 0; d < 16; d += 4) {
        float4 v = make_float4(goalv[d], goalv[d+1], goalv[d+2], goalv[d+3]);
        *(float4*)(out_goals + row*16 + d) = v;
    }
    out_lpg[row] = -0.5f*(lsum + 16.f*LOG2PI);
}

// ---------------------------------------------------------------------------
// Action + value decoder: goal_obs(80) -> [ad: 80 relu -> 16], [vd: 80 relu -> 1]
// ---------------------------------------------------------------------------
__global__ __launch_bounds__(256) void dec_av_kernel(
    const float* __restrict__ goals,
    const float* __restrict__ obs,
    const float* __restrict__ aeps,
    const float* __restrict__ aw1, const float* __restrict__ ab1,
    const float* __restrict__ aw2, const float* __restrict__ ab2,
    const float* __restrict__ vw1, const float* __restrict__ vb1,
    const float* __restrict__ vw2, const float* __restrict__ vb2,
    float* __restrict__ out_actions, float* __restrict__ out_lpa,
    float* __restrict__ out_values)
{
    __shared__ float AW1[80*80];
    __shared__ float VW1[80*80];
    __shared__ float AW2[16*80];
    __shared__ float VW2[80];
    __shared__ float AB1[80];
    __shared__ float VB1[80];
    __shared__ float AB2[16];
    const int tid = threadIdx.x;
    for (int e = tid; e < 80*80; e += 256) { AW1[e] = aw1[e]; VW1[e] = vw1[e]; }
    for (int e = tid; e < 16*80; e += 256) AW2[e] = aw2[e];
    if (tid < 80) { VW2[tid] = vw2[tid]; AB1[tid] = ab1[tid]; VB1[tid] = vb1[tid]; }
    if (tid < 16) AB2[tid] = ab2[tid];
    __syncthreads();

    const size_t row = (size_t)blockIdx.x*256 + tid;

    float hid[80];
    #pragma unroll
    for (int jj = 0; jj < 80; ++jj) hid[jj] = AB1[jj];
    for (int k = 0; k < 80; k += 4) {
        float4 xv;
        if (k < 16) xv = *(const float4*)(goals + row*16 + k);
        else        xv = *(const float4*)(obs + row*64 + (k - 16));
        #pragma unroll
        for (int jj = 0; jj < 80; ++jj) {
            float s = hid[jj];
            s = fmaf(AW1[jj*80 + k],     xv.x, s);
            s = fmaf(AW1[jj*80 + k + 1], xv.y, s);
            s = fmaf(AW1[jj*80 + k + 2], xv.z, s);
            s = fmaf(AW1[jj*80 + k + 3], xv.w, s);
            hid[jj] = s;
        }
    }
    #pragma unroll
    for (int jj = 0; jj < 80; ++jj) hid[jj] = fmaxf(hid[jj], 0.f);

    float am[8], asd[8];
    #pragma unroll
    for (int jj = 0; jj < 8; ++jj) {
        float s = AB2[jj];
        #pragma unroll
        for (int k = 0; k < 80; ++k) s = fmaf(AW2[jj*80 + k], hid[k], s);
        am[jj] = s;
    }
    #pragma unroll
    for (int jj = 0; jj < 8; ++jj) {
        float s = AB2[8 + jj];
        #pragma unroll
        for (int k = 0; k < 80; ++k) s = fmaf(AW2[(8+jj)*80 + k], hid[k], s);
        asd[jj] = s;
    }

    float ae[8];
    #pragma unroll
    for (int d = 0; d < 8; d += 4) {
        float4 v = *(const float4*)(aeps + row*8 + d);
        ae[d]=v.x; ae[d+1]=v.y; ae[d+2]=v.z; ae[d+3]=v.w;
    }
    float lsum = 0.f;
    float actv[8];
    #pragma unroll
    for (int d = 0; d < 8; ++d) {
        float avar = fmaf(asd[d], asd[d], 0.001f);
        float act  = fmaf(sqrtf(avar), ae[d], am[d]);
        actv[d] = act;
        float dd = act - am[d];
        lsum += dd*dd/avar + __logf(avar);
    }
    #pragma unroll
    for (int d = 0; d < 8; d += 4) {
        float4 v = make_float4(actv[d], actv[d+1], actv[d+2], actv[d+3]);
        *(float4*)(out_actions + row*8 + d) = v;
    }
    out_lpa[row] = -0.5f*(lsum + 8.f*LOG2PI);

    float vh[80];
    #pragma unroll
    for (int jj = 0; jj < 80; ++jj) vh[jj] = VB1[jj];
    for (int k = 0; k < 80; k += 4) {
        float4 xv;
        if (k < 16) xv = *(const float4*)(goals + row*16 + k);
        else        xv = *(const float4*)(obs + row*64 + (k - 16));
        #pragma unroll
        for (int jj = 0; jj < 80; ++jj) {
            float s = vh[jj];
            s = fmaf(VW1[jj*80 + k],     xv.x, s);
            s = fmaf(VW1[jj*80 + k + 1], xv.y, s);
            s = fmaf(VW1[jj*80 + k + 2], xv.z, s);
            s = fmaf(VW1[jj*80 + k + 3], xv.w, s);
            vh[jj] = s;
        }
    }
    float v = vb2[0];
    #pragma unroll
    for (int jj = 0; jj < 80; ++jj) v = fmaf(VW2[jj], fmaxf(vh[jj], 0.f), v);
    out_values[row] = v;
}

// ---------------------------------------------------------------------------
// lp decoder: full_lat_obs(192) -> 192 relu -> 1.
// ---------------------------------------------------------------------------
__global__ __launch_bounds__(256) void dec_lpv_kernel(
    const float* __restrict__ h2,
    const float* __restrict__ obs,
    const float* __restrict__ w1, const float* __restrict__ b1,
    const float* __restrict__ w2, const float* __restrict__ b2,
    float* __restrict__ out_lpv)
{
    __shared__ __align__(16) float W1s[64*192];
    __shared__ float B1[192];
    __shared__ float W2[192];
    const int tid = threadIdx.x;
    const int l = tid & 3;
    const size_t item = (size_t)blockIdx.x*64 + (tid >> 2);
    if (tid < 192) { B1[tid] = b1[tid]; W2[tid] = w2[tid]; }

    float x[48];
    #pragma unroll
    for (int q = 0; q < 12; ++q) {
        int gk = l*48 + q*4;
        float4 v;
        if (gk < 128) v = *(const float4*)(h2 + item*128 + gk);
        else          v = *(const float4*)(obs + item*64 + (gk - 128));
        x[q*4]=v.x; x[q*4+1]=v.y; x[q*4+2]=v.z; x[q*4+3]=v.w;
    }

    float acc = 0.f;
    for (int j0 = 0; j0 < 192; j0 += 64) {
        __syncthreads();
        for (int e = tid; e < 64*48; e += 256) {
            int rr = e / 48, q = e - rr*48;
            *(float4*)&W1s[rr*192 + q*4] =
                *(const float4*)&w1[(size_t)(j0 + rr)*192 + q*4];
        }
        __syncthreads();
        for (int jj = 0; jj < 64; ++jj) {
            const float* wr = W1s + jj*192 + l*48;
            float p = 0.f;
            #pragma unroll
            for (int q = 0; q < 12; ++q) {
                float4 wv = *(const float4*)(wr + q*4);
                p = fmaf(wv.x, x[q*4],     p);
                p = fmaf(wv.y, x[q*4 + 1], p);
                p = fmaf(wv.z, x[q*4 + 2], p);
                p = fmaf(wv.w, x[q*4 + 3], p);
            }
            p += __shfl_xor(p, 1);
            p += __shfl_xor(p, 2);
            float h = fmaxf(p + B1[j0 + jj], 0.f);
            acc = fmaf(W2[j0 + jj], h, acc);
        }
    }
    if (l == 0) out_lpv[item] = acc + b2[0];
}

// ---------------------------------------------------------------------------
extern "C" void kernel_launch(void* const* d_in, const int* in_sizes, int n_in,
                              void* d_out, int out_size, void* d_ws, size_t ws_size,
                              hipStream_t stream)
{
    (void)in_sizes; (void)n_in; (void)out_size;

    const float* obs    = (const float*)d_in[0];
    const float* lps    = (const float*)d_in[1];
    const float* geps   = (const float*)d_in[2];
    const float* aeps   = (const float*)d_in[3];
    const float* h0     = (const float*)d_in[4];
    const float* c0     = (const float*)d_in[5];
    const float* w_ih0  = (const float*)d_in[6];
    const float* b_ih0  = (const float*)d_in[7];
    const float* w_hh0  = (const float*)d_in[8];
    const float* b_hh0  = (const float*)d_in[9];
    const float* w_ih1  = (const float*)d_in[10];
    const float* b_ih1  = (const float*)d_in[11];
    const float* w_hh1  = (const float*)d_in[12];
    const float* b_hh1  = (const float*)d_in[13];
    const float* gd_w1  = (const float*)d_in[14];
    const float* gd_b1  = (const float*)d_in[15];
    const float* gd_w2  = (const float*)d_in[16];
    const float* gd_b2  = (const float*)d_in[17];
    const float* ad_w1  = (const float*)d_in[18];
    const float* ad_b1  = (const float*)d_in[19];
    const float* ad_w2  = (const float*)d_in[20];
    const float* ad_b2  = (const float*)d_in[21];
    const float* vd_w1  = (const float*)d_in[22];
    const float* vd_b1  = (const float*)d_in[23];
    const float* vd_w2  = (const float*)d_in[24];
    const float* vd_b2  = (const float*)d_in[25];
    const float* lpd_w1 = (const float*)d_in[26];
    const float* lpd_b1 = (const float*)d_in[27];
    const float* lpd_w2 = (const float*)d_in[28];
    const float* lpd_b2 = (const float*)d_in[29];

    float* out         = (float*)d_out;
    float* out_actions = out;                 // (T,B,8)
    float* out_lpa     = out + 2097152;       // (T,B)
    float* out_goals   = out + 2359296;       // (T,B,16)
    float* out_lpg     = out + 6553600;       // (T,B)
    float* out_values  = out + 6815744;       // (T,B,1)
    float* out_lpv     = out + 7077888;       // (T,B,1)

    // --- workspace: xb (bf16 obs, full T) + per-chunk h1(bf16)/h2(f32) ---
    const size_t XB_ELEMS    = (size_t)TT * BB * 64;       // bf16
    const size_t STATE_ELEMS = 2ull * BB * 128;            // per h or c
    int C = 0;
    for (int c = TT; c >= 8; c >>= 1) {
        size_t need = XB_ELEMS*2
                    + (size_t)c * BB * 128 * 2     // h1 bf16
                    + (size_t)c * BB * 128 * 4     // h2 f32
                    + 2 * STATE_ELEMS * 4;
        if (need <= ws_size) { C = c; break; }
    }
    if (C == 0) return;
    const int nchunks = TT / C;

    unsigned short* xb  = (unsigned short*)d_ws;
    unsigned short* h1c = xb + XB_ELEMS;
    float* h2c     = (float*)(h1c + (size_t)C * BB * 128);
    float* h_state = h2c + (size_t)C * BB * 128;
    float* c_state = h_state + STATE_ELEMS;

    const dim3 blk(256);

    cvt_bf16_kernel<<<dim3((int)(XB_ELEMS/8/256)), blk, 0, stream>>>(obs, xb);
    init_state_kernel<<<dim3((int)(STATE_ELEMS/256)), blk, 0, stream>>>(
        h0, c0, h_state, c_state);

    for (int ch = 0; ch < nchunks; ++ch) {
        const size_t crow0 = (size_t)ch * C * BB;
        const int rows = C * BB;

        lstm0_kernel<<<dim3(BB), dim3(512), 0, stream>>>(
            xb + crow0*64, lps + crow0, w_ih0, w_hh0, b_ih0, b_hh0,
            h_state, c_state, h1c, C);

        lstm1_kernel<<<dim3(BB), dim3(512), 0, stream>>>(
            h1c, w_ih1, w_hh1, b_ih1, b_hh1,
            h_state + BB*128, c_state + BB*128, h2c, C);

        dec_goal_kernel<<<dim3(rows/256), blk, 0, stream>>>(
            h2c, geps + crow0*16, gd_w1, gd_b1, gd_w2, gd_b2,
            out_goals + crow0*16, out_lpg + crow0);

        dec_av_kernel<<<dim3(rows/256), blk, 0, stream>>>(
            out_goals + crow0*16, obs + crow0*64, aeps + crow0*8,
            ad_w1, ad_b1, ad_w2, ad_b2, vd_w1, vd_b1, vd_w2, vd_b2,
            out_actions + crow0*8, out_lpa + crow0, out_values + crow0);

        dec_lpv_kernel<<<dim3(rows/64), blk, 0, stream>>>(
            h2c, obs + crow0*64, lpd_w1, lpd_b1, lpd_w2, lpd_b2,
            out_lpv + crow0);
    }
}